// Round 15
// baseline (2445.675 us; speedup 1.0000x reference)
//
#include <hip/hip_runtime.h>

// ---------------------------------------------------------------------------
// arGDPmax_net: 80-step coupled GRU (SDC 128 / world 3968 rows, H=512)
// + segment-max coupling + per-step MLP head.
//
// Round-15 = R14 (2062us) + BK=128 double-chunk staging in k_big:
//  - world path: 2 K-chunks staged per barrier round (64KB LDS), 4 rounds
//    (was 8). sdc path: 2 chunks/round, 8 rounds (was 16). Chunk-ascending
//    compute order preserves the exact K sequence -> bit-identical.
// Core invariants: 2 launches/step, NO intra-kernel cross-block sync
// (R3..R6 multi-ms spin stalls), sdc GRU INSIDE k_big (overlap, R9/R12),
// batched k_mlp every 8 steps (R11), single-barrier G (R13), XCD remaps
// (R14), gload16 staging, XOR swizzle.
// ---------------------------------------------------------------------------

typedef __attribute__((ext_vector_type(8))) short short8;
typedef __attribute__((ext_vector_type(4))) float f32x4;
typedef unsigned short u16;
typedef unsigned int u32;

#define DEV __device__ __forceinline__

constexpr int S  = 128;
constexpr int NR = 4096;
constexpr int H  = 512;
constexpr int TH = 1536;
constexpr int SLOT = NR * H;
constexpr int SEGSZ = S * H;       // u32 elems per segmax buffer

struct P {
  const float *goals, *dyn, *ccls, *inte;
  const int *seg;
  const float *sdc_h0, *wld_h0;
  const float *golW, *golb;
  const float *sdcbi, *sdcbh, *wldbi, *wldbh;
  const float *sdco1b, *sdco2W, *sdco2b;
  const float *wldo1b, *wldo2W, *wldo2b;
  const float *sdcWi, *sdcWh, *wldWi, *wldWh, *sdco1W, *wldo1W;
  float *out;
  float *whf;      // [2][4096][512] f32 carried state
  u16   *ring;     // [8][4096][512] bf16 state history
  u16   *enc;      // [4096][512] bf16 encoder output (dead after t=0)
  u16   *WT;       // 4 x [1536][512] bf16: sdcWiT, sdcWhT, wldWiT, wldWhT
  u16   *o1T;      // 2 x [512][512] bf16
  float *G;        // [128][1536] f32: sh@wld_Wi + bi
  u32   *segb;     // [2][128][512] flipped-uint segmax buffers
  u16   *segbf;    // [128][512] bf16 of prev-step segmax (aliases enc)
  float *part;     // [2][32768][2] f32 MLP partials (aliases enc+128KB)
  int t;
};

DEV u16 f2bf(float f) {
  u32 u = __float_as_uint(f);
  u32 r = u + 0x7FFFu + ((u >> 16) & 1u);
  return (u16)(r >> 16);
}
DEV u32 flipf(float f) {
  u32 u = __float_as_uint(f);
  return (u & 0x80000000u) ? ~u : (u | 0x80000000u);
}
DEV float unflip(u32 s) {
  u32 u = (s & 0x80000000u) ? (s & 0x7FFFFFFFu) : ~s;
  return __uint_as_float(u);
}
DEV float sigm(float x)  { return 1.0f / (1.0f + __expf(-x)); }
DEV float tanh_(float x) { return 2.0f / (1.0f + __expf(-2.0f * x)) - 1.0f; }

DEV f32x4 mfma16(short8 a, short8 b, f32x4 c) {
  return __builtin_amdgcn_mfma_f32_16x16x32_bf16(a, b, c, 0, 0, 0);
}

// async global->LDS, 16B per lane. LDS dest = wave-uniform base + lane*16.
DEV void gload16(const void* g, void* l) {
  __builtin_amdgcn_global_load_lds(
      (const __attribute__((address_space(1))) void*)g,
      (__attribute__((address_space(3))) void*)l, 16, 0, 0);
}

// fragment read honoring the XOR swizzle; row stride 64 elems (128B).
DEV short8 lds_frag(const u16* lds, int row, int g) {
  return *(const short8*)(lds + row * 64 + ((g ^ (row & 7)) << 3));
}

// ---------------------------------------------------------------------------
// k_prep: weight transposes (f32 LDS [64][65]), encoder (float4), h0 copy
// (float4), segb[0] clear. Grid 1028.
// ---------------------------------------------------------------------------
__global__ __launch_bounds__(256) void k_prep(P p) {
  const int b = blockIdx.x, tid = threadIdx.x;
  __shared__ float ltf[64 * 65];
  if (b < 896) {
    int nt, kt, Nn; const float* src; u16* dst;
    if (b < 768) {
      int m = b / 192, t2 = b % 192;
      nt = t2 % 24; kt = t2 / 24; Nn = TH;
      src = (m == 0) ? p.sdcWi : (m == 1) ? p.sdcWh : (m == 2) ? p.wldWi : p.wldWh;
      dst = p.WT + m * TH * H;
    } else {
      int bb = b - 768, m = bb / 64, t2 = bb % 64;
      nt = t2 % 8; kt = t2 / 8; Nn = H;
      src = m ? p.wldo1W : p.sdco1W;
      dst = p.o1T + m * H * H;
    }
    for (int it = 0; it < 16; ++it) {
      int kl = it * 4 + (tid >> 6), nl = tid & 63;
      ltf[nl * 65 + kl] = src[(kt * 64 + kl) * Nn + nt * 64 + nl];
    }
    __syncthreads();
    for (int it = 0; it < 2; ++it) {
      int nl = it * 32 + (tid >> 3), k8 = (tid & 7) * 8;
      short8 v;
#pragma unroll
      for (int e = 0; e < 8; ++e) v[e] = (short)f2bf(ltf[nl * 65 + k8 + e]);
      *(short8*)(dst + (nt * 64 + nl) * H + kt * 64 + k8) = v;
    }
  } else if (b < 960) {                      // encoder, float4
    int r0 = (b - 896) * 64;
    for (int i = 0; i < 32; ++i) {
      int idx = i * 256 + tid;
      int row = r0 + (idx >> 7), c4 = (idx & 127) * 4;
      float4 v;
      if (c4 < 128) {
        float g0 = p.goals[row * 2], g1 = p.goals[row * 2 + 1];
        v.x = g0 * p.golW[c4]     + g1 * p.golW[128 + c4]     + p.golb[c4];
        v.y = g0 * p.golW[c4 + 1] + g1 * p.golW[128 + c4 + 1] + p.golb[c4 + 1];
        v.z = g0 * p.golW[c4 + 2] + g1 * p.golW[128 + c4 + 2] + p.golb[c4 + 2];
        v.w = g0 * p.golW[c4 + 3] + g1 * p.golW[128 + c4 + 3] + p.golb[c4 + 3];
      } else if (c4 < 256) v = *(const float4*)(p.dyn  + row * 128 + c4 - 128);
      else if (c4 < 384)   v = *(const float4*)(p.ccls + row * 128 + c4 - 256);
      else                 v = *(const float4*)(p.inte + row * 128 + c4 - 384);
      ushort4 o;
      o.x = f2bf(v.x); o.y = f2bf(v.y); o.z = f2bf(v.z); o.w = f2bf(v.w);
      *(ushort4*)(p.enc + row * H + c4) = o;
    }
  } else if (b < 1024) {                     // h0 copy, float4
    int r0 = (b - 960) * 64;
    for (int i = 0; i < 32; ++i) {
      int idx = i * 256 + tid;
      int row = r0 + (idx >> 7), c4 = (idx & 127) * 4;
      float4 v = (row < S) ? *(const float4*)(p.sdc_h0 + row * H + c4)
                           : *(const float4*)(p.wld_h0 + (row - S) * H + c4);
      *(float4*)(p.whf + SLOT + row * H + c4) = v;
      ushort4 o;
      o.x = f2bf(v.x); o.y = f2bf(v.y); o.z = f2bf(v.z); o.w = f2bf(v.w);
      *(ushort4*)(p.ring + 7 * SLOT + row * H + c4) = o;
    }
  } else {                                   // clear segb[0]
    int base = (b - 1024) * 16384;
    for (int i = 0; i < 64; ++i) p.segb[base + i * 256 + tid] = 0u;
  }
}

// ---------------------------------------------------------------------------
// k_big0: step 0 (full gi from enc + gh from h0, all 4096 rows).
// Grid 512 x 512 threads (8 waves, 2M x 4N), gload16 staging.
// ---------------------------------------------------------------------------
__global__ __launch_bounds__(512) void k_big0(P p) {
  const int b = blockIdx.x, tid = threadIdx.x;
  const int rt = b >> 3, cg = b & 7;
  const bool sdc = rt < 2;
  const int wv = tid >> 6, wm = wv >> 2, wn = wv & 3;
  const int lr = (tid >> 4) & 3, lc = tid & 15;
  __shared__ u16 sm[16384];
  const u16* WiT = p.WT + (sdc ? 0 : 2) * TH * H;
  const u16* WhT = p.WT + (sdc ? 1 : 3) * TH * H;

  f32x4 ai[3][2], ah[3][2];
  f32x4 zero = {0.f, 0.f, 0.f, 0.f};
#pragma unroll
  for (int g = 0; g < 3; ++g)
#pragma unroll
    for (int mt = 0; mt < 2; ++mt) { ai[g][mt] = zero; ah[g][mt] = zero; }

  for (int pass = 0; pass < 2; ++pass) {
    const u16* A  = pass ? (p.ring + 7 * SLOT + rt * 64 * H) : (p.enc + rt * 64 * H);
    const u16* BT = pass ? WhT : WiT;
    for (int kc = 0; kc < H; kc += 64) {
      __syncthreads();
#pragma unroll
      for (int it = 0; it < 4; ++it) {
        int u = it * 512 + tid;
        int gs = (u ^ (u >> 3)) & 7;
        const u16* src;
        if (u < 512) {
          src = A + (u >> 3) * H + kc + gs * 8;
        } else {
          int v = u - 512;
          int g = v >> 9, m = (v >> 3) & 63;
          src = BT + (g * H + cg * 64 + m) * H + kc + gs * 8;
        }
        gload16(src, sm + (it * 512 + (tid & 448)) * 8);
      }
      __syncthreads();
#pragma unroll
      for (int s2 = 0; s2 < 2; ++s2) {
        const int gk = s2 * 4 + lr;
        short8 av[2], bv[3];
#pragma unroll
        for (int mt = 0; mt < 2; ++mt)
          av[mt] = lds_frag(sm, wm * 32 + mt * 16 + lc, gk);
#pragma unroll
        for (int g = 0; g < 3; ++g)
          bv[g] = lds_frag(sm + 4096 + g * 4096, wn * 16 + lc, gk);
#pragma unroll
        for (int g = 0; g < 3; ++g)
#pragma unroll
          for (int mt = 0; mt < 2; ++mt) {
            f32x4 r = pass ? ah[g][mt] : ai[g][mt];
            r = mfma16(av[mt], bv[g], r);
            if (pass) ah[g][mt] = r; else ai[g][mt] = r;
          }
      }
    }
  }
  const float* bi = sdc ? p.sdcbi : p.wldbi;
  const float* bh = sdc ? p.sdcbh : p.wldbh;
  const int col = cg * 64 + wn * 16 + lc;
  const float bir = bi[col], biz = bi[H + col], bin = bi[2 * H + col];
  const float bhr = bh[col], bhz = bh[H + col], bhn = bh[2 * H + col];
#pragma unroll
  for (int mt = 0; mt < 2; ++mt)
#pragma unroll
    for (int i = 0; i < 4; ++i) {
      int grow = rt * 64 + wm * 32 + mt * 16 + lr * 4 + i;
      float r = sigm(ai[0][mt][i] + bir + ah[0][mt][i] + bhr);
      float z = sigm(ai[1][mt][i] + biz + ah[1][mt][i] + bhz);
      float n = tanh_(ai[2][mt][i] + bin + r * (ah[2][mt][i] + bhn));
      float h = p.whf[SLOT + grow * H + col];
      float h2 = (1.f - z) * n + z * h;
      p.whf[grow * H + col] = h2;
      p.ring[grow * H + col] = f2bf(h2);
      if (!sdc) {
        int scen = p.seg[grow - S];
        atomicMax(p.segb + scen * H + col, flipf(h2));
      }
    }
}

// ---------------------------------------------------------------------------
// k_small(t), grid 160 x 512 threads (R13 verbatim):
//   blocks 0..95  : clear segb[t&1]; segbf cvt; G GEMM single-burst/1-barrier.
//   blocks 96..159: deferred k_mlp2 (active when t%8==0).
// ---------------------------------------------------------------------------
__global__ __launch_bounds__(512) void k_small(P p) {
  const int b = blockIdx.x, tid = threadIdx.x;
  __shared__ u16 sm[49152];           // 96 KB: A 8x[64][64] + B 8x[32][64]
  if (b >= 96) {  // ---- deferred k_mlp2 ----
    if ((p.t & 7) != 0 || p.t < 8) return;
    const int base = p.t - 8;
    const int gt2 = (b - 96) * 512 + tid;   // 0..32767
    for (int i = gt2; i < 65536; i += 32768) {
      int r = i >> 1, od = i & 1;
      int row = r & 4095, slot = r >> 12;
      float v = p.part[i] + p.part[65536 + i];
      v += (row < S ? p.sdco2b : p.wldo2b)[od];
      p.out[row * 160 + (base + slot) * 2 + od] = v;
    }
    return;
  }
  const int gtid = b * 512 + tid;
  u32* sb = p.segb + (p.t & 1) * SEGSZ;
  if (gtid < 16384) ((uint4*)sb)[gtid] = make_uint4(0u, 0u, 0u, 0u);
  const u32* sp = p.segb + ((p.t - 1) & 1) * SEGSZ;
  if (gtid < 16384) {
    uint4 q = ((const uint4*)sp)[gtid];
    u32 lo = (u32)f2bf(unflip(q.x)) | ((u32)f2bf(unflip(q.y)) << 16);
    u32 hi = (u32)f2bf(unflip(q.z)) | ((u32)f2bf(unflip(q.w)) << 16);
    ((u32*)p.segbf)[gtid * 2]     = lo;
    ((u32*)p.segbf)[gtid * 2 + 1] = hi;
  }
  const int rh = b / 48, nc = b % 48;
  const int wv = tid >> 6, wm = wv >> 1, wn = wv & 1;
  const int lr = (tid >> 4) & 3, lc = tid & 15;
  const u16* Ab = p.ring + ((p.t - 1) & 7) * SLOT + rh * 64 * H;
  const u16* Wb = p.WT + 2 * TH * H;  // wld_WiT

#pragma unroll
  for (int it = 0; it < 12; ++it) {
    int u = it * 512 + tid;             // 0..6143
    const u16* src;
    if (u < 4096) {
      int kc = u >> 9, v = u & 511;
      int m = v >> 3, g = v & 7, gs = g ^ (m & 7);
      src = Ab + m * H + kc * 64 + gs * 8;
    } else {
      int u2 = u - 4096;
      int kc = u2 >> 8, v = u2 & 255;
      int m = v >> 3, g = v & 7, gs = g ^ (m & 7);
      src = Wb + (nc * 32 + m) * H + kc * 64 + gs * 8;
    }
    gload16(src, sm + (it * 512 + (tid & 448)) * 8);
  }
  __syncthreads();                      // the ONLY barrier

  f32x4 acc = {0.f, 0.f, 0.f, 0.f};
#pragma unroll
  for (int kc = 0; kc < 8; ++kc)
#pragma unroll
    for (int s2 = 0; s2 < 2; ++s2) {
      const int gk = s2 * 4 + lr;
      short8 av = lds_frag(sm + kc * 4096, wm * 16 + lc, gk);
      short8 bv = lds_frag(sm + 32768 + kc * 2048, wn * 16 + lc, gk);
      acc = mfma16(av, bv, acc);
    }
  const int colb = nc * 32 + wn * 16 + lc;
  const float bi = p.wldbi[colb];
#pragma unroll
  for (int i = 0; i < 4; ++i)
    p.G[(rh * 64 + wm * 16 + lr * 4 + i) * TH + colb] = acc[i] + bi;
}

// ---------------------------------------------------------------------------
// k_big(t), 512 threads/block, grid 560, BK=128 double-chunk staging:
//   blocks 0..63  : sdc GRU (FIRST). waves 0..3, 2 chunks/round (8 rounds).
//   blocks 64..559: world GRU, XCD-grouped remap, 2 chunks/round (4 rounds),
//                   64KB LDS: chunk c at sm + c*16384 (A 4096 + B 3x4096).
// ---------------------------------------------------------------------------
__global__ __launch_bounds__(512) void k_big(P p) {
  const int b = blockIdx.x, tid = threadIdx.x;
  const int lr = (tid >> 4) & 3, lc = tid & 15;
  __shared__ u16 sm[32768];           // 64 KB
  const int tp = (p.t - 1) & 7, tn = p.t & 7;
  const float* whfP = p.whf + ((p.t - 1) & 1) * SLOT;
  float* whfN = p.whf + (p.t & 1) * SLOT;
  u16* ringN = p.ring + tn * SLOT;

  if (b >= 64) {  // ---- world GRU ----
    const int wb = b - 64;
    const int w2 = (wb & 7) * 62 + (wb >> 3);   // XCD-grouping remap
    const int rt = w2 >> 3, cg = w2 & 7;
    const int wv = tid >> 6, wm = wv >> 2, wn = wv & 3;
    const u16* Abase = p.ring + tp * SLOT + (S + rt * 64) * H;
    const u16* Bbase = p.WT + 3 * TH * H;      // wld_WhT
    f32x4 acc[3][2];
    f32x4 zero = {0.f, 0.f, 0.f, 0.f};
#pragma unroll
    for (int g = 0; g < 3; ++g) { acc[g][0] = zero; acc[g][1] = zero; }

    for (int kc = 0; kc < H; kc += 128) {
      __syncthreads();
#pragma unroll
      for (int it = 0; it < 8; ++it) {
        int u = it * 512 + tid;               // 0..4095
        int c = u >> 11, v = u & 2047;        // c uniform per it
        int gs = (v ^ (v >> 3)) & 7;
        const u16* src;
        if (v < 512) {
          src = Abase + (v >> 3) * H + kc + c * 64 + gs * 8;
        } else {
          int v2 = v - 512;
          int g = v2 >> 9, m = (v2 >> 3) & 63;
          src = Bbase + (g * H + cg * 64 + m) * H + kc + c * 64 + gs * 8;
        }
        gload16(src, sm + (it * 512 + (tid & 448)) * 8);
      }
      __syncthreads();
#pragma unroll
      for (int c = 0; c < 2; ++c)
#pragma unroll
        for (int s2 = 0; s2 < 2; ++s2) {
          const int gk = s2 * 4 + lr;
          short8 av[2], bv[3];
#pragma unroll
          for (int mt = 0; mt < 2; ++mt)
            av[mt] = lds_frag(sm + c * 16384, wm * 32 + mt * 16 + lc, gk);
#pragma unroll
          for (int g = 0; g < 3; ++g)
            bv[g] = lds_frag(sm + c * 16384 + 4096 + g * 4096, wn * 16 + lc, gk);
#pragma unroll
          for (int g = 0; g < 3; ++g)
#pragma unroll
            for (int mt = 0; mt < 2; ++mt) acc[g][mt] = mfma16(av[mt], bv[g], acc[g][mt]);
        }
    }
    const int col = cg * 64 + wn * 16 + lc;
    const float bhr = p.wldbh[col], bhz = p.wldbh[H + col], bhn = p.wldbh[2 * H + col];
    u32* sb = p.segb + (p.t & 1) * SEGSZ;
    int curSc = -1; float curMx = 0.f;
#pragma unroll
    for (int mt = 0; mt < 2; ++mt)
#pragma unroll
      for (int i = 0; i < 4; ++i) {
        int wrow = rt * 64 + wm * 32 + mt * 16 + lr * 4 + i;
        int grow = S + wrow;
        int scen = p.seg[wrow];
        const float* Gr = p.G + scen * TH;
        float r = sigm(Gr[col]          + acc[0][mt][i] + bhr);
        float z = sigm(Gr[H + col]      + acc[1][mt][i] + bhz);
        float n = tanh_(Gr[2 * H + col] + r * (acc[2][mt][i] + bhn));
        float h = whfP[grow * H + col];
        float h2 = (1.f - z) * n + z * h;
        whfN[grow * H + col] = h2;
        ringN[grow * H + col] = f2bf(h2);
        if (scen == curSc) curMx = fmaxf(curMx, h2);
        else {
          if (curSc >= 0) atomicMax(sb + curSc * H + col, flipf(curMx));
          curSc = scen; curMx = h2;
        }
      }
    atomicMax(sb + curSc * H + col, flipf(curMx));
  } else {        // ---- sdc GRU (blocks 0..63): waves 0..3 only ----
    const int w = tid >> 6;
    if (w >= 4) return;                 // exited waves don't join barriers
    const int ab = b, rh = ab >> 5, cgx = ab & 31;
    f32x4 ai[3], ah[3];
    f32x4 zero = {0.f, 0.f, 0.f, 0.f};
#pragma unroll
    for (int g = 0; g < 3; ++g) { ai[g] = zero; ah[g] = zero; }

    for (int pass = 0; pass < 2; ++pass) {
      const u16* A  = pass ? (p.ring + tp * SLOT + rh * 64 * H)
                           : (p.segbf + rh * 64 * H);
      const u16* BT = p.WT + (pass ? 1 : 0) * TH * H;   // sdcWhT : sdcWiT
      for (int kc = 0; kc < H; kc += 128) {
        __syncthreads();
        // stage 2 chunks: per chunk 896 units (A 512 + B 384); 1792 total.
#pragma unroll
        for (int it = 0; it < 7; ++it) {
          int u = it * 256 + tid;             // 0..1791, c uniform per wave
          int c = (u >= 896) ? 1 : 0;
          int v = u - c * 896;
          int gs = (v ^ (v >> 3)) & 7;
          const u16* src;
          if (v < 512) {
            src = A + (v >> 3) * H + kc + c * 64 + gs * 8;
          } else {
            int m = (v - 512) >> 3;           // 0..47
            src = BT + ((m >> 4) * H + cgx * 16 + (m & 15)) * H + kc + c * 64 + gs * 8;
          }
          gload16(src, sm + (it * 256 + (tid & 192)) * 8);
        }
        __syncthreads();
#pragma unroll
        for (int c = 0; c < 2; ++c)
#pragma unroll
          for (int s2 = 0; s2 < 2; ++s2) {
            const int gk = s2 * 4 + lr;
            short8 a = lds_frag(sm + c * 7168, w * 16 + lc, gk);
#pragma unroll
            for (int g = 0; g < 3; ++g) {
              f32x4 r = pass ? ah[g] : ai[g];
              r = mfma16(a, lds_frag(sm + c * 7168 + 4096 + g * 1024, lc, gk), r);
              if (pass) ah[g] = r; else ai[g] = r;
            }
          }
      }
    }
    const int col = cgx * 16 + lc;
    const float bir = p.sdcbi[col], biz = p.sdcbi[H + col], bin = p.sdcbi[2 * H + col];
    const float bhr = p.sdcbh[col], bhz = p.sdcbh[H + col], bhn = p.sdcbh[2 * H + col];
#pragma unroll
    for (int i = 0; i < 4; ++i) {
      int srow = rh * 64 + w * 16 + lr * 4 + i;
      float r = sigm(ai[0][i] + bir + ah[0][i] + bhr);
      float z = sigm(ai[1][i] + biz + ah[1][i] + bhz);
      float n = tanh_(ai[2][i] + bin + r * (ah[2][i] + bhn));
      float h = whfP[srow * H + col];
      float h2 = (1.f - z) * n + z * h;
      whfN[srow * H + col] = h2;
      ringN[srow * H + col] = f2bf(h2);
    }
  }
}

// ---------------------------------------------------------------------------
// k_mlp: 512 blocks, slot-per-XCD swizzle (XCD x <- ring slot x), 512 thr
// (2wm x 4wn), tile 128x256, 48KB LDS. Layer1 GEMM + fused leaky+layer2
// partials (2-way).
// ---------------------------------------------------------------------------
__global__ __launch_bounds__(512) void k_mlp(P p) {
  const int b = blockIdx.x, tid = threadIdx.x;
  const int w2 = (b & 7) * 64 + (b >> 3);    // slot-per-XCD remap
  const int rt = w2 >> 1, ct = w2 & 1;
  const int slot = rt >> 5, rtile = rt & 31;
  const bool sdc = (rtile == 0);
  const int wv = tid >> 6, wm = wv >> 2, wn = wv & 3;
  const int lr = (tid >> 4) & 3, lc = tid & 15;
  __shared__ u16 sm[24576];           // A 128x64 (8192) + B 256x64 (16384)
  const u16* A  = p.ring + slot * SLOT + rtile * 128 * H;
  const u16* Bb = p.o1T + (sdc ? 0 : 1) * H * H + (ct * 256) * H;
  const float* o1b = sdc ? p.sdco1b : p.wldo1b;
  const float* o2W = sdc ? p.sdco2W : p.wldo2W;

  f32x4 acc[4][4];
  f32x4 zero = {0.f, 0.f, 0.f, 0.f};
#pragma unroll
  for (int mt = 0; mt < 4; ++mt)
#pragma unroll
    for (int c2 = 0; c2 < 4; ++c2) acc[mt][c2] = zero;

  for (int kc = 0; kc < H; kc += 64) {
    __syncthreads();
#pragma unroll
    for (int it = 0; it < 6; ++it) {
      int u = it * 512 + tid;           // 0..3071
      int gs = (u ^ (u >> 3)) & 7;
      const u16* src;
      if (u < 1024) src = A  + (u >> 3) * H + kc + gs * 8;
      else          src = Bb + ((u - 1024) >> 3) * H + kc + gs * 8;
      gload16(src, sm + (it * 512 + (tid & 448)) * 8);
    }
    __syncthreads();
#pragma unroll
    for (int s2 = 0; s2 < 2; ++s2) {
      const int gk = s2 * 4 + lr;
      short8 av[4], bv[4];
#pragma unroll
      for (int mt = 0; mt < 4; ++mt)
        av[mt] = lds_frag(sm, wm * 64 + mt * 16 + lc, gk);
#pragma unroll
      for (int c2 = 0; c2 < 4; ++c2)
        bv[c2] = lds_frag(sm + 8192, wn * 64 + c2 * 16 + lc, gk);
#pragma unroll
      for (int mt = 0; mt < 4; ++mt)
#pragma unroll
        for (int c2 = 0; c2 < 4; ++c2) acc[mt][c2] = mfma16(av[mt], bv[c2], acc[mt][c2]);
    }
  }
  __syncthreads();
  float* red = (float*)sm;              // red[wn][128][2] = 4KB
#pragma unroll
  for (int mt = 0; mt < 4; ++mt) {
    float q0[4] = {0.f, 0.f, 0.f, 0.f}, q1[4] = {0.f, 0.f, 0.f, 0.f};
#pragma unroll
    for (int c2 = 0; c2 < 4; ++c2) {
      int col = ct * 256 + wn * 64 + c2 * 16 + lc;
      float b1 = o1b[col], w0 = o2W[col * 2], w1 = o2W[col * 2 + 1];
#pragma unroll
      for (int i = 0; i < 4; ++i) {
        float v = acc[mt][c2][i] + b1;
        v = v > 0.f ? v : 0.1f * v;
        q0[i] += v * w0; q1[i] += v * w1;
      }
    }
#pragma unroll
    for (int off = 1; off < 16; off <<= 1)
#pragma unroll
      for (int i = 0; i < 4; ++i) {
        q0[i] += __shfl_xor(q0[i], off);
        q1[i] += __shfl_xor(q1[i], off);
      }
    if (lc == 0)
#pragma unroll
      for (int i = 0; i < 4; ++i) {
        int row = wm * 64 + mt * 16 + lr * 4 + i;
        red[(wn * 128 + row) * 2 + 0] = q0[i];
        red[(wn * 128 + row) * 2 + 1] = q1[i];
      }
  }
  __syncthreads();
  if (tid < 256) {
    int row = tid >> 1, od = tid & 1;
    float sum = red[(0 * 128 + row) * 2 + od] + red[(1 * 128 + row) * 2 + od] +
                red[(2 * 128 + row) * 2 + od] + red[(3 * 128 + row) * 2 + od];
    int r = slot * 4096 + rtile * 128 + row;
    p.part[ct * 65536 + r * 2 + od] = sum;
  }
}

// k_mlp2: out = sum of 2 col-half partials + o2 bias (final batch only).
__global__ __launch_bounds__(256) void k_mlp2(P p) {
  const int gtid = blockIdx.x * 256 + threadIdx.x;
  for (int i = gtid; i < 65536; i += 16384) {
    int r = i >> 1, od = i & 1;
    int row = r & 4095, slot = r >> 12;
    float v = p.part[i] + p.part[65536 + i];
    v += (row < S ? p.sdco2b : p.wldo2b)[od];
    p.out[row * 160 + (p.t + slot) * 2 + od] = v;
  }
}

// ---------------------------------------------------------------------------
extern "C" void kernel_launch(void* const* d_in, const int* in_sizes, int n_in,
                              void* d_out, int out_size, void* d_ws, size_t ws_size,
                              hipStream_t stream) {
  P prm;
  prm.goals  = (const float*)d_in[0];
  prm.dyn    = (const float*)d_in[1];
  prm.ccls   = (const float*)d_in[2];
  prm.inte   = (const float*)d_in[3];
  prm.seg    = (const int*)  d_in[4];
  prm.sdc_h0 = (const float*)d_in[5];
  prm.wld_h0 = (const float*)d_in[6];
  prm.golW   = (const float*)d_in[7];
  prm.golb   = (const float*)d_in[8];
  prm.sdcWi  = (const float*)d_in[9];
  prm.sdcWh  = (const float*)d_in[10];
  prm.sdcbi  = (const float*)d_in[11];
  prm.sdcbh  = (const float*)d_in[12];
  prm.wldWi  = (const float*)d_in[13];
  prm.wldWh  = (const float*)d_in[14];
  prm.wldbi  = (const float*)d_in[15];
  prm.wldbh  = (const float*)d_in[16];
  prm.sdco1W = (const float*)d_in[17];
  prm.sdco1b = (const float*)d_in[18];
  prm.sdco2W = (const float*)d_in[19];
  prm.sdco2b = (const float*)d_in[20];
  prm.wldo1W = (const float*)d_in[21];
  prm.wldo1b = (const float*)d_in[22];
  prm.wldo2W = (const float*)d_in[23];
  prm.wldo2b = (const float*)d_in[24];
  prm.out = (float*)d_out;

  char* ws = (char*)d_ws;
  prm.whf   = (float*)(ws + 0);              // 16,777,216 B
  prm.ring  = (u16*)  (ws + 16777216);       // 33,554,432 B
  prm.enc   = (u16*)  (ws + 50331648);       //  4,194,304 B
  prm.WT    = (u16*)  (ws + 54525952);       //  6,291,456 B
  prm.o1T   = (u16*)  (ws + 60817408);       //  1,048,576 B
  prm.G     = (float*)(ws + 61865984);       //    786,432 B
  prm.segb  = (u32*)  (ws + 62652416);       //    524,288 B (x2 buffers)
  prm.segbf = (u16*)  (ws + 50331648);           // aliases enc (dead after t=0)
  prm.part  = (float*)(ws + 50331648 + 131072);  // aliases enc+128KB (512 KB)

  prm.t = 0;
  k_prep<<<1028, 256, 0, stream>>>(prm);
  k_big0<<<512, 512, 0, stream>>>(prm);
  for (int t = 1; t < 80; ++t) {
    prm.t = t;
    k_small<<<160, 512, 0, stream>>>(prm);
    k_big<<<560, 512, 0, stream>>>(prm);
    if ((t & 7) == 7) {
      k_mlp<<<512, 512, 0, stream>>>(prm);
    }
  }
  P pm = prm;
  pm.t = 72;
  k_mlp2<<<64, 256, 0, stream>>>(pm);   // final batch (t=72..79)
}

// Round 16
// 2060.868 us; speedup vs baseline: 1.1867x; 1.1867x over previous
//
#include <hip/hip_runtime.h>

// ---------------------------------------------------------------------------
// arGDPmax_net: 80-step coupled GRU (SDC 128 / world 3968 rows, H=512)
// + segment-max coupling + per-step MLP head.
//
// Round-16 = exact revert to R14 (2062us, best). R15's BK=128 k_big
// regressed (+383us) via the documented m132 occupancy cliff (64KB LDS ->
// 2 blocks/CU, was 4). This config is the measured plateau:
//  - 2 launches/step, NO intra-kernel cross-block sync (R3..R6 stalls).
//  - sdc GRU INSIDE k_big, overlapped with world blocks (R9/R12 lesson).
//  - single-barrier G kernel (R13), XCD-aware remaps (R14),
//    batched k_mlp every 8 steps + deferred mlp2 fold (R11).
//  - gload16 width-16 staging everywhere, XOR-swizzled global sources.
// ---------------------------------------------------------------------------

typedef __attribute__((ext_vector_type(8))) short short8;
typedef __attribute__((ext_vector_type(4))) float f32x4;
typedef unsigned short u16;
typedef unsigned int u32;

#define DEV __device__ __forceinline__

constexpr int S  = 128;
constexpr int NR = 4096;
constexpr int H  = 512;
constexpr int TH = 1536;
constexpr int SLOT = NR * H;
constexpr int SEGSZ = S * H;       // u32 elems per segmax buffer

struct P {
  const float *goals, *dyn, *ccls, *inte;
  const int *seg;
  const float *sdc_h0, *wld_h0;
  const float *golW, *golb;
  const float *sdcbi, *sdcbh, *wldbi, *wldbh;
  const float *sdco1b, *sdco2W, *sdco2b;
  const float *wldo1b, *wldo2W, *wldo2b;
  const float *sdcWi, *sdcWh, *wldWi, *wldWh, *sdco1W, *wldo1W;
  float *out;
  float *whf;      // [2][4096][512] f32 carried state
  u16   *ring;     // [8][4096][512] bf16 state history
  u16   *enc;      // [4096][512] bf16 encoder output (dead after t=0)
  u16   *WT;       // 4 x [1536][512] bf16: sdcWiT, sdcWhT, wldWiT, wldWhT
  u16   *o1T;      // 2 x [512][512] bf16
  float *G;        // [128][1536] f32: sh@wld_Wi + bi
  u32   *segb;     // [2][128][512] flipped-uint segmax buffers
  u16   *segbf;    // [128][512] bf16 of prev-step segmax (aliases enc)
  float *part;     // [2][32768][2] f32 MLP partials (aliases enc+128KB)
  int t;
};

DEV u16 f2bf(float f) {
  u32 u = __float_as_uint(f);
  u32 r = u + 0x7FFFu + ((u >> 16) & 1u);
  return (u16)(r >> 16);
}
DEV u32 flipf(float f) {
  u32 u = __float_as_uint(f);
  return (u & 0x80000000u) ? ~u : (u | 0x80000000u);
}
DEV float unflip(u32 s) {
  u32 u = (s & 0x80000000u) ? (s & 0x7FFFFFFFu) : ~s;
  return __uint_as_float(u);
}
DEV float sigm(float x)  { return 1.0f / (1.0f + __expf(-x)); }
DEV float tanh_(float x) { return 2.0f / (1.0f + __expf(-2.0f * x)) - 1.0f; }

DEV f32x4 mfma16(short8 a, short8 b, f32x4 c) {
  return __builtin_amdgcn_mfma_f32_16x16x32_bf16(a, b, c, 0, 0, 0);
}

// async global->LDS, 16B per lane. LDS dest = wave-uniform base + lane*16.
DEV void gload16(const void* g, void* l) {
  __builtin_amdgcn_global_load_lds(
      (const __attribute__((address_space(1))) void*)g,
      (__attribute__((address_space(3))) void*)l, 16, 0, 0);
}

// fragment read honoring the XOR swizzle; row stride 64 elems (128B).
DEV short8 lds_frag(const u16* lds, int row, int g) {
  return *(const short8*)(lds + row * 64 + ((g ^ (row & 7)) << 3));
}

// ---------------------------------------------------------------------------
// k_prep: weight transposes (f32 LDS [64][65]), encoder (float4), h0 copy
// (float4), segb[0] clear. Grid 1028.
// ---------------------------------------------------------------------------
__global__ __launch_bounds__(256) void k_prep(P p) {
  const int b = blockIdx.x, tid = threadIdx.x;
  __shared__ float ltf[64 * 65];
  if (b < 896) {
    int nt, kt, Nn; const float* src; u16* dst;
    if (b < 768) {
      int m = b / 192, t2 = b % 192;
      nt = t2 % 24; kt = t2 / 24; Nn = TH;
      src = (m == 0) ? p.sdcWi : (m == 1) ? p.sdcWh : (m == 2) ? p.wldWi : p.wldWh;
      dst = p.WT + m * TH * H;
    } else {
      int bb = b - 768, m = bb / 64, t2 = bb % 64;
      nt = t2 % 8; kt = t2 / 8; Nn = H;
      src = m ? p.wldo1W : p.sdco1W;
      dst = p.o1T + m * H * H;
    }
    for (int it = 0; it < 16; ++it) {
      int kl = it * 4 + (tid >> 6), nl = tid & 63;
      ltf[nl * 65 + kl] = src[(kt * 64 + kl) * Nn + nt * 64 + nl];
    }
    __syncthreads();
    for (int it = 0; it < 2; ++it) {
      int nl = it * 32 + (tid >> 3), k8 = (tid & 7) * 8;
      short8 v;
#pragma unroll
      for (int e = 0; e < 8; ++e) v[e] = (short)f2bf(ltf[nl * 65 + k8 + e]);
      *(short8*)(dst + (nt * 64 + nl) * H + kt * 64 + k8) = v;
    }
  } else if (b < 960) {                      // encoder, float4
    int r0 = (b - 896) * 64;
    for (int i = 0; i < 32; ++i) {
      int idx = i * 256 + tid;
      int row = r0 + (idx >> 7), c4 = (idx & 127) * 4;
      float4 v;
      if (c4 < 128) {
        float g0 = p.goals[row * 2], g1 = p.goals[row * 2 + 1];
        v.x = g0 * p.golW[c4]     + g1 * p.golW[128 + c4]     + p.golb[c4];
        v.y = g0 * p.golW[c4 + 1] + g1 * p.golW[128 + c4 + 1] + p.golb[c4 + 1];
        v.z = g0 * p.golW[c4 + 2] + g1 * p.golW[128 + c4 + 2] + p.golb[c4 + 2];
        v.w = g0 * p.golW[c4 + 3] + g1 * p.golW[128 + c4 + 3] + p.golb[c4 + 3];
      } else if (c4 < 256) v = *(const float4*)(p.dyn  + row * 128 + c4 - 128);
      else if (c4 < 384)   v = *(const float4*)(p.ccls + row * 128 + c4 - 256);
      else                 v = *(const float4*)(p.inte + row * 128 + c4 - 384);
      ushort4 o;
      o.x = f2bf(v.x); o.y = f2bf(v.y); o.z = f2bf(v.z); o.w = f2bf(v.w);
      *(ushort4*)(p.enc + row * H + c4) = o;
    }
  } else if (b < 1024) {                     // h0 copy, float4
    int r0 = (b - 960) * 64;
    for (int i = 0; i < 32; ++i) {
      int idx = i * 256 + tid;
      int row = r0 + (idx >> 7), c4 = (idx & 127) * 4;
      float4 v = (row < S) ? *(const float4*)(p.sdc_h0 + row * H + c4)
                           : *(const float4*)(p.wld_h0 + (row - S) * H + c4);
      *(float4*)(p.whf + SLOT + row * H + c4) = v;
      ushort4 o;
      o.x = f2bf(v.x); o.y = f2bf(v.y); o.z = f2bf(v.z); o.w = f2bf(v.w);
      *(ushort4*)(p.ring + 7 * SLOT + row * H + c4) = o;
    }
  } else {                                   // clear segb[0]
    int base = (b - 1024) * 16384;
    for (int i = 0; i < 64; ++i) p.segb[base + i * 256 + tid] = 0u;
  }
}

// ---------------------------------------------------------------------------
// k_big0: step 0 (full gi from enc + gh from h0, all 4096 rows).
// Grid 512 x 512 threads (8 waves, 2M x 4N), gload16 staging.
// ---------------------------------------------------------------------------
__global__ __launch_bounds__(512) void k_big0(P p) {
  const int b = blockIdx.x, tid = threadIdx.x;
  const int rt = b >> 3, cg = b & 7;
  const bool sdc = rt < 2;
  const int wv = tid >> 6, wm = wv >> 2, wn = wv & 3;
  const int lr = (tid >> 4) & 3, lc = tid & 15;
  __shared__ u16 sm[16384];
  const u16* WiT = p.WT + (sdc ? 0 : 2) * TH * H;
  const u16* WhT = p.WT + (sdc ? 1 : 3) * TH * H;

  f32x4 ai[3][2], ah[3][2];
  f32x4 zero = {0.f, 0.f, 0.f, 0.f};
#pragma unroll
  for (int g = 0; g < 3; ++g)
#pragma unroll
    for (int mt = 0; mt < 2; ++mt) { ai[g][mt] = zero; ah[g][mt] = zero; }

  for (int pass = 0; pass < 2; ++pass) {
    const u16* A  = pass ? (p.ring + 7 * SLOT + rt * 64 * H) : (p.enc + rt * 64 * H);
    const u16* BT = pass ? WhT : WiT;
    for (int kc = 0; kc < H; kc += 64) {
      __syncthreads();
#pragma unroll
      for (int it = 0; it < 4; ++it) {
        int u = it * 512 + tid;
        int gs = (u ^ (u >> 3)) & 7;
        const u16* src;
        if (u < 512) {
          src = A + (u >> 3) * H + kc + gs * 8;
        } else {
          int v = u - 512;
          int g = v >> 9, m = (v >> 3) & 63;
          src = BT + (g * H + cg * 64 + m) * H + kc + gs * 8;
        }
        gload16(src, sm + (it * 512 + (tid & 448)) * 8);
      }
      __syncthreads();
#pragma unroll
      for (int s2 = 0; s2 < 2; ++s2) {
        const int gk = s2 * 4 + lr;
        short8 av[2], bv[3];
#pragma unroll
        for (int mt = 0; mt < 2; ++mt)
          av[mt] = lds_frag(sm, wm * 32 + mt * 16 + lc, gk);
#pragma unroll
        for (int g = 0; g < 3; ++g)
          bv[g] = lds_frag(sm + 4096 + g * 4096, wn * 16 + lc, gk);
#pragma unroll
        for (int g = 0; g < 3; ++g)
#pragma unroll
          for (int mt = 0; mt < 2; ++mt) {
            f32x4 r = pass ? ah[g][mt] : ai[g][mt];
            r = mfma16(av[mt], bv[g], r);
            if (pass) ah[g][mt] = r; else ai[g][mt] = r;
          }
      }
    }
  }
  const float* bi = sdc ? p.sdcbi : p.wldbi;
  const float* bh = sdc ? p.sdcbh : p.wldbh;
  const int col = cg * 64 + wn * 16 + lc;
  const float bir = bi[col], biz = bi[H + col], bin = bi[2 * H + col];
  const float bhr = bh[col], bhz = bh[H + col], bhn = bh[2 * H + col];
#pragma unroll
  for (int mt = 0; mt < 2; ++mt)
#pragma unroll
    for (int i = 0; i < 4; ++i) {
      int grow = rt * 64 + wm * 32 + mt * 16 + lr * 4 + i;
      float r = sigm(ai[0][mt][i] + bir + ah[0][mt][i] + bhr);
      float z = sigm(ai[1][mt][i] + biz + ah[1][mt][i] + bhz);
      float n = tanh_(ai[2][mt][i] + bin + r * (ah[2][mt][i] + bhn));
      float h = p.whf[SLOT + grow * H + col];
      float h2 = (1.f - z) * n + z * h;
      p.whf[grow * H + col] = h2;
      p.ring[grow * H + col] = f2bf(h2);
      if (!sdc) {
        int scen = p.seg[grow - S];
        atomicMax(p.segb + scen * H + col, flipf(h2));
      }
    }
}

// ---------------------------------------------------------------------------
// k_small(t), grid 160 x 512 threads:
//   blocks 0..95  : clear segb[t&1]; segbf cvt; G GEMM single-burst/1-barrier.
//   blocks 96..159: deferred k_mlp2 (active when t%8==0).
// ---------------------------------------------------------------------------
__global__ __launch_bounds__(512) void k_small(P p) {
  const int b = blockIdx.x, tid = threadIdx.x;
  __shared__ u16 sm[49152];           // 96 KB: A 8x[64][64] + B 8x[32][64]
  if (b >= 96) {  // ---- deferred k_mlp2 ----
    if ((p.t & 7) != 0 || p.t < 8) return;
    const int base = p.t - 8;
    const int gt2 = (b - 96) * 512 + tid;   // 0..32767
    for (int i = gt2; i < 65536; i += 32768) {
      int r = i >> 1, od = i & 1;
      int row = r & 4095, slot = r >> 12;
      float v = p.part[i] + p.part[65536 + i];
      v += (row < S ? p.sdco2b : p.wldo2b)[od];
      p.out[row * 160 + (base + slot) * 2 + od] = v;
    }
    return;
  }
  const int gtid = b * 512 + tid;
  u32* sb = p.segb + (p.t & 1) * SEGSZ;
  if (gtid < 16384) ((uint4*)sb)[gtid] = make_uint4(0u, 0u, 0u, 0u);
  const u32* sp = p.segb + ((p.t - 1) & 1) * SEGSZ;
  if (gtid < 16384) {
    uint4 q = ((const uint4*)sp)[gtid];
    u32 lo = (u32)f2bf(unflip(q.x)) | ((u32)f2bf(unflip(q.y)) << 16);
    u32 hi = (u32)f2bf(unflip(q.z)) | ((u32)f2bf(unflip(q.w)) << 16);
    ((u32*)p.segbf)[gtid * 2]     = lo;
    ((u32*)p.segbf)[gtid * 2 + 1] = hi;
  }
  const int rh = b / 48, nc = b % 48;
  const int wv = tid >> 6, wm = wv >> 1, wn = wv & 1;
  const int lr = (tid >> 4) & 3, lc = tid & 15;
  const u16* Ab = p.ring + ((p.t - 1) & 7) * SLOT + rh * 64 * H;
  const u16* Wb = p.WT + 2 * TH * H;  // wld_WiT

#pragma unroll
  for (int it = 0; it < 12; ++it) {
    int u = it * 512 + tid;             // 0..6143
    const u16* src;
    if (u < 4096) {
      int kc = u >> 9, v = u & 511;
      int m = v >> 3, g = v & 7, gs = g ^ (m & 7);
      src = Ab + m * H + kc * 64 + gs * 8;
    } else {
      int u2 = u - 4096;
      int kc = u2 >> 8, v = u2 & 255;
      int m = v >> 3, g = v & 7, gs = g ^ (m & 7);
      src = Wb + (nc * 32 + m) * H + kc * 64 + gs * 8;
    }
    gload16(src, sm + (it * 512 + (tid & 448)) * 8);
  }
  __syncthreads();                      // the ONLY barrier

  f32x4 acc = {0.f, 0.f, 0.f, 0.f};
#pragma unroll
  for (int kc = 0; kc < 8; ++kc)
#pragma unroll
    for (int s2 = 0; s2 < 2; ++s2) {
      const int gk = s2 * 4 + lr;
      short8 av = lds_frag(sm + kc * 4096, wm * 16 + lc, gk);
      short8 bv = lds_frag(sm + 32768 + kc * 2048, wn * 16 + lc, gk);
      acc = mfma16(av, bv, acc);
    }
  const int colb = nc * 32 + wn * 16 + lc;
  const float bi = p.wldbi[colb];
#pragma unroll
  for (int i = 0; i < 4; ++i)
    p.G[(rh * 64 + wm * 16 + lr * 4 + i) * TH + colb] = acc[i] + bi;
}

// ---------------------------------------------------------------------------
// k_big(t), 512 threads/block, grid 560:
//   blocks 0..63  : sdc GRU (FIRST: latency-chain head start). waves 0..3
//                   active, gload16 from segbf/ring.
//   blocks 64..559: world GRU, XCD-grouped remap (x=wb%8,j=wb/8,w=x*62+j):
//                   each XCD owns ~8 consecutive rt -> A-tile L2 reuse.
// ---------------------------------------------------------------------------
__global__ __launch_bounds__(512) void k_big(P p) {
  const int b = blockIdx.x, tid = threadIdx.x;
  const int lr = (tid >> 4) & 3, lc = tid & 15;
  __shared__ u16 sm[16384];           // 32 KB
  const int tp = (p.t - 1) & 7, tn = p.t & 7;
  const float* whfP = p.whf + ((p.t - 1) & 1) * SLOT;
  float* whfN = p.whf + (p.t & 1) * SLOT;
  u16* ringN = p.ring + tn * SLOT;

  if (b >= 64) {  // ---- world GRU ----
    const int wb = b - 64;
    const int w2 = (wb & 7) * 62 + (wb >> 3);   // XCD-grouping remap
    const int rt = w2 >> 3, cg = w2 & 7;
    const int wv = tid >> 6, wm = wv >> 2, wn = wv & 3;
    const u16* Abase = p.ring + tp * SLOT + (S + rt * 64) * H;
    const u16* Bbase = p.WT + 3 * TH * H;      // wld_WhT
    f32x4 acc[3][2];
    f32x4 zero = {0.f, 0.f, 0.f, 0.f};
#pragma unroll
    for (int g = 0; g < 3; ++g) { acc[g][0] = zero; acc[g][1] = zero; }

    for (int kc = 0; kc < H; kc += 64) {
      __syncthreads();
#pragma unroll
      for (int it = 0; it < 4; ++it) {
        int u = it * 512 + tid;
        int gs = (u ^ (u >> 3)) & 7;
        const u16* src;
        if (u < 512) {
          src = Abase + (u >> 3) * H + kc + gs * 8;
        } else {
          int v = u - 512;
          int g = v >> 9, m = (v >> 3) & 63;
          src = Bbase + (g * H + cg * 64 + m) * H + kc + gs * 8;
        }
        gload16(src, sm + (it * 512 + (tid & 448)) * 8);
      }
      __syncthreads();
#pragma unroll
      for (int s2 = 0; s2 < 2; ++s2) {
        const int gk = s2 * 4 + lr;
        short8 av[2], bv[3];
#pragma unroll
        for (int mt = 0; mt < 2; ++mt)
          av[mt] = lds_frag(sm, wm * 32 + mt * 16 + lc, gk);
#pragma unroll
        for (int g = 0; g < 3; ++g)
          bv[g] = lds_frag(sm + 4096 + g * 4096, wn * 16 + lc, gk);
#pragma unroll
        for (int g = 0; g < 3; ++g)
#pragma unroll
          for (int mt = 0; mt < 2; ++mt) acc[g][mt] = mfma16(av[mt], bv[g], acc[g][mt]);
      }
    }
    const int col = cg * 64 + wn * 16 + lc;
    const float bhr = p.wldbh[col], bhz = p.wldbh[H + col], bhn = p.wldbh[2 * H + col];
    u32* sb = p.segb + (p.t & 1) * SEGSZ;
    int curSc = -1; float curMx = 0.f;
#pragma unroll
    for (int mt = 0; mt < 2; ++mt)
#pragma unroll
      for (int i = 0; i < 4; ++i) {
        int wrow = rt * 64 + wm * 32 + mt * 16 + lr * 4 + i;
        int grow = S + wrow;
        int scen = p.seg[wrow];
        const float* Gr = p.G + scen * TH;
        float r = sigm(Gr[col]          + acc[0][mt][i] + bhr);
        float z = sigm(Gr[H + col]      + acc[1][mt][i] + bhz);
        float n = tanh_(Gr[2 * H + col] + r * (acc[2][mt][i] + bhn));
        float h = whfP[grow * H + col];
        float h2 = (1.f - z) * n + z * h;
        whfN[grow * H + col] = h2;
        ringN[grow * H + col] = f2bf(h2);
        if (scen == curSc) curMx = fmaxf(curMx, h2);
        else {
          if (curSc >= 0) atomicMax(sb + curSc * H + col, flipf(curMx));
          curSc = scen; curMx = h2;
        }
      }
    atomicMax(sb + curSc * H + col, flipf(curMx));
  } else {        // ---- sdc GRU (blocks 0..63): waves 0..3 only ----
    const int w = tid >> 6;
    if (w >= 4) return;                 // exited waves don't join barriers
    const int ab = b, rh = ab >> 5, cgx = ab & 31;
    f32x4 ai[3], ah[3];
    f32x4 zero = {0.f, 0.f, 0.f, 0.f};
#pragma unroll
    for (int g = 0; g < 3; ++g) { ai[g] = zero; ah[g] = zero; }

    for (int pass = 0; pass < 2; ++pass) {
      const u16* A  = pass ? (p.ring + tp * SLOT + rh * 64 * H)
                           : (p.segbf + rh * 64 * H);
      const u16* BT = p.WT + (pass ? 1 : 0) * TH * H;   // sdcWhT : sdcWiT
      for (int kc = 0; kc < H; kc += 64) {
        __syncthreads();
#pragma unroll
        for (int it = 0; it < 4; ++it) {
          int u = it * 256 + tid;
          if (u < 896) {
            int gs = (u ^ (u >> 3)) & 7;
            const u16* src;
            if (u < 512) {
              src = A + (u >> 3) * H + kc + gs * 8;
            } else {
              int v = u - 512;
              int m = v >> 3;            // 0..47
              src = BT + ((m >> 4) * H + cgx * 16 + (m & 15)) * H + kc + gs * 8;
            }
            gload16(src, sm + (it * 256 + (tid & 192)) * 8);
          }
        }
        __syncthreads();
#pragma unroll
        for (int s2 = 0; s2 < 2; ++s2) {
          const int gk = s2 * 4 + lr;
          short8 a = lds_frag(sm, w * 16 + lc, gk);
#pragma unroll
          for (int g = 0; g < 3; ++g) {
            f32x4 r = pass ? ah[g] : ai[g];
            r = mfma16(a, lds_frag(sm + 4096, g * 16 + lc, gk), r);
            if (pass) ah[g] = r; else ai[g] = r;
          }
        }
      }
    }
    const int col = cgx * 16 + lc;
    const float bir = p.sdcbi[col], biz = p.sdcbi[H + col], bin = p.sdcbi[2 * H + col];
    const float bhr = p.sdcbh[col], bhz = p.sdcbh[H + col], bhn = p.sdcbh[2 * H + col];
#pragma unroll
    for (int i = 0; i < 4; ++i) {
      int srow = rh * 64 + w * 16 + lr * 4 + i;
      float r = sigm(ai[0][i] + bir + ah[0][i] + bhr);
      float z = sigm(ai[1][i] + biz + ah[1][i] + bhz);
      float n = tanh_(ai[2][i] + bin + r * (ah[2][i] + bhn));
      float h = whfP[srow * H + col];
      float h2 = (1.f - z) * n + z * h;
      whfN[srow * H + col] = h2;
      ringN[srow * H + col] = f2bf(h2);
    }
  }
}

// ---------------------------------------------------------------------------
// k_mlp: 512 blocks, slot-per-XCD swizzle (XCD x <- ring slot x), 512 thr
// (2wm x 4wn), tile 128x256, 48KB LDS. Layer1 GEMM + fused leaky+layer2
// partials (2-way).
// ---------------------------------------------------------------------------
__global__ __launch_bounds__(512) void k_mlp(P p) {
  const int b = blockIdx.x, tid = threadIdx.x;
  const int w2 = (b & 7) * 64 + (b >> 3);    // slot-per-XCD remap
  const int rt = w2 >> 1, ct = w2 & 1;
  const int slot = rt >> 5, rtile = rt & 31;
  const bool sdc = (rtile == 0);
  const int wv = tid >> 6, wm = wv >> 2, wn = wv & 3;
  const int lr = (tid >> 4) & 3, lc = tid & 15;
  __shared__ u16 sm[24576];           // A 128x64 (8192) + B 256x64 (16384)
  const u16* A  = p.ring + slot * SLOT + rtile * 128 * H;
  const u16* Bb = p.o1T + (sdc ? 0 : 1) * H * H + (ct * 256) * H;
  const float* o1b = sdc ? p.sdco1b : p.wldo1b;
  const float* o2W = sdc ? p.sdco2W : p.wldo2W;

  f32x4 acc[4][4];
  f32x4 zero = {0.f, 0.f, 0.f, 0.f};
#pragma unroll
  for (int mt = 0; mt < 4; ++mt)
#pragma unroll
    for (int c2 = 0; c2 < 4; ++c2) acc[mt][c2] = zero;

  for (int kc = 0; kc < H; kc += 64) {
    __syncthreads();
#pragma unroll
    for (int it = 0; it < 6; ++it) {
      int u = it * 512 + tid;           // 0..3071
      int gs = (u ^ (u >> 3)) & 7;
      const u16* src;
      if (u < 1024) src = A  + (u >> 3) * H + kc + gs * 8;
      else          src = Bb + ((u - 1024) >> 3) * H + kc + gs * 8;
      gload16(src, sm + (it * 512 + (tid & 448)) * 8);
    }
    __syncthreads();
#pragma unroll
    for (int s2 = 0; s2 < 2; ++s2) {
      const int gk = s2 * 4 + lr;
      short8 av[4], bv[4];
#pragma unroll
      for (int mt = 0; mt < 4; ++mt)
        av[mt] = lds_frag(sm, wm * 64 + mt * 16 + lc, gk);
#pragma unroll
      for (int c2 = 0; c2 < 4; ++c2)
        bv[c2] = lds_frag(sm + 8192, wn * 64 + c2 * 16 + lc, gk);
#pragma unroll
      for (int mt = 0; mt < 4; ++mt)
#pragma unroll
        for (int c2 = 0; c2 < 4; ++c2) acc[mt][c2] = mfma16(av[mt], bv[c2], acc[mt][c2]);
    }
  }
  __syncthreads();
  float* red = (float*)sm;              // red[wn][128][2] = 4KB
#pragma unroll
  for (int mt = 0; mt < 4; ++mt) {
    float q0[4] = {0.f, 0.f, 0.f, 0.f}, q1[4] = {0.f, 0.f, 0.f, 0.f};
#pragma unroll
    for (int c2 = 0; c2 < 4; ++c2) {
      int col = ct * 256 + wn * 64 + c2 * 16 + lc;
      float b1 = o1b[col], w0 = o2W[col * 2], w1 = o2W[col * 2 + 1];
#pragma unroll
      for (int i = 0; i < 4; ++i) {
        float v = acc[mt][c2][i] + b1;
        v = v > 0.f ? v : 0.1f * v;
        q0[i] += v * w0; q1[i] += v * w1;
      }
    }
#pragma unroll
    for (int off = 1; off < 16; off <<= 1)
#pragma unroll
      for (int i = 0; i < 4; ++i) {
        q0[i] += __shfl_xor(q0[i], off);
        q1[i] += __shfl_xor(q1[i], off);
      }
    if (lc == 0)
#pragma unroll
      for (int i = 0; i < 4; ++i) {
        int row = wm * 64 + mt * 16 + lr * 4 + i;
        red[(wn * 128 + row) * 2 + 0] = q0[i];
        red[(wn * 128 + row) * 2 + 1] = q1[i];
      }
  }
  __syncthreads();
  if (tid < 256) {
    int row = tid >> 1, od = tid & 1;
    float sum = red[(0 * 128 + row) * 2 + od] + red[(1 * 128 + row) * 2 + od] +
                red[(2 * 128 + row) * 2 + od] + red[(3 * 128 + row) * 2 + od];
    int r = slot * 4096 + rtile * 128 + row;
    p.part[ct * 65536 + r * 2 + od] = sum;
  }
}

// k_mlp2: out = sum of 2 col-half partials + o2 bias (final batch only).
__global__ __launch_bounds__(256) void k_mlp2(P p) {
  const int gtid = blockIdx.x * 256 + threadIdx.x;
  for (int i = gtid; i < 65536; i += 16384) {
    int r = i >> 1, od = i & 1;
    int row = r & 4095, slot = r >> 12;
    float v = p.part[i] + p.part[65536 + i];
    v += (row < S ? p.sdco2b : p.wldo2b)[od];
    p.out[row * 160 + (p.t + slot) * 2 + od] = v;
  }
}

// ---------------------------------------------------------------------------
extern "C" void kernel_launch(void* const* d_in, const int* in_sizes, int n_in,
                              void* d_out, int out_size, void* d_ws, size_t ws_size,
                              hipStream_t stream) {
  P prm;
  prm.goals  = (const float*)d_in[0];
  prm.dyn    = (const float*)d_in[1];
  prm.ccls   = (const float*)d_in[2];
  prm.inte   = (const float*)d_in[3];
  prm.seg    = (const int*)  d_in[4];
  prm.sdc_h0 = (const float*)d_in[5];
  prm.wld_h0 = (const float*)d_in[6];
  prm.golW   = (const float*)d_in[7];
  prm.golb   = (const float*)d_in[8];
  prm.sdcWi  = (const float*)d_in[9];
  prm.sdcWh  = (const float*)d_in[10];
  prm.sdcbi  = (const float*)d_in[11];
  prm.sdcbh  = (const float*)d_in[12];
  prm.wldWi  = (const float*)d_in[13];
  prm.wldWh  = (const float*)d_in[14];
  prm.wldbi  = (const float*)d_in[15];
  prm.wldbh  = (const float*)d_in[16];
  prm.sdco1W = (const float*)d_in[17];
  prm.sdco1b = (const float*)d_in[18];
  prm.sdco2W = (const float*)d_in[19];
  prm.sdco2b = (const float*)d_in[20];
  prm.wldo1W = (const float*)d_in[21];
  prm.wldo1b = (const float*)d_in[22];
  prm.wldo2W = (const float*)d_in[23];
  prm.wldo2b = (const float*)d_in[24];
  prm.out = (float*)d_out;

  char* ws = (char*)d_ws;
  prm.whf   = (float*)(ws + 0);              // 16,777,216 B
  prm.ring  = (u16*)  (ws + 16777216);       // 33,554,432 B
  prm.enc   = (u16*)  (ws + 50331648);       //  4,194,304 B
  prm.WT    = (u16*)  (ws + 54525952);       //  6,291,456 B
  prm.o1T   = (u16*)  (ws + 60817408);       //  1,048,576 B
  prm.G     = (float*)(ws + 61865984);       //    786,432 B
  prm.segb  = (u32*)  (ws + 62652416);       //    524,288 B (x2 buffers)
  prm.segbf = (u16*)  (ws + 50331648);           // aliases enc (dead after t=0)
  prm.part  = (float*)(ws + 50331648 + 131072);  // aliases enc+128KB (512 KB)

  prm.t = 0;
  k_prep<<<1028, 256, 0, stream>>>(prm);
  k_big0<<<512, 512, 0, stream>>>(prm);
  for (int t = 1; t < 80; ++t) {
    prm.t = t;
    k_small<<<160, 512, 0, stream>>>(prm);
    k_big<<<560, 512, 0, stream>>>(prm);
    if ((t & 7) == 7) {
      k_mlp<<<512, 512, 0, stream>>>(prm);
    }
  }
  P pm = prm;
  pm.t = 72;
  k_mlp2<<<64, 256, 0, stream>>>(pm);   // final batch (t=72..79)
}